// Round 5
// baseline (313.877 us; speedup 1.0000x reference)
//
#include <hip/hip_runtime.h>

static constexpr int N  = 100000;
static constexpr int E  = 1600000;
static constexpr int B  = 256;

static constexpr int NBLK   = 250;            // partition blocks
static constexpr int CHUNK  = E / NBLK;       // 6400 edges per block
static constexpr int PERT   = CHUNK / B;      // 25 edges per thread
static constexpr int NBUCK  = 782;            // ceil(N/128) buckets of 128 nodes
static constexpr int NCNT   = NBUCK * NBLK;   // 195500 count-matrix entries
static constexpr int NSB    = (NCNT + B - 1) / B;  // scan blocks

__device__ __forceinline__ int gbase(const int* scanned, const int* bsum, int idx) {
    return scanned[idx] + bsum[idx >> 8];
}

// ---- phase A: per-block bucket histogram ------------------------------------

__global__ void kA_hist(const int* __restrict__ dst, int* __restrict__ counts) {
    __shared__ int hist[NBUCK];
    int t = threadIdx.x, blk = blockIdx.x;
    for (int i = t; i < NBUCK; i += B) hist[i] = 0;
    __syncthreads();
    int eb = blk * CHUNK;
#pragma unroll
    for (int k = 0; k < PERT; ++k) {
        int d = dst[eb + k * B + t];
        atomicAdd(&hist[d >> 7], 1);
    }
    __syncthreads();
    for (int b = t; b < NBUCK; b += B) counts[b * NBLK + blk] = hist[b];
}

// ---- scan -------------------------------------------------------------------

__global__ void ks1(const int* __restrict__ counts, int* __restrict__ scanned,
                    int* __restrict__ bsum) {
    __shared__ int s[B];
    int t = threadIdx.x;
    int g = blockIdx.x * B + t;
    s[t] = (g < NCNT) ? counts[g] : 0;
    __syncthreads();
    for (int off = 1; off < B; off <<= 1) {
        int v = (t >= off) ? s[t - off] : 0;
        __syncthreads();
        s[t] += v;
        __syncthreads();
    }
    if (g < NCNT) scanned[g] = (t == 0) ? 0 : s[t - 1];
    if (t == B - 1) bsum[blockIdx.x] = s[t];
}

__global__ void ks2(int* __restrict__ bsum) {
    __shared__ int s[1024];
    int t = threadIdx.x;
    s[t] = (t < NSB) ? bsum[t] : 0;
    __syncthreads();
    for (int off = 1; off < 1024; off <<= 1) {
        int v = (t >= off) ? s[t - off] : 0;
        __syncthreads();
        s[t] += v;
        __syncthreads();
    }
    if (t < NSB) bsum[t] = (t == 0) ? 0 : s[t - 1];
}

// ---- phase C: stable partition with LDS staging -----------------------------

__global__ void kC_scatter(const int* __restrict__ src, const int* __restrict__ dst,
                           const int* __restrict__ scanned, const int* __restrict__ bsum,
                           int* __restrict__ packed) {
    __shared__ int lbase[NBUCK];
    __shared__ int cnt2[NBUCK];
    __shared__ int gb[NBUCK];
    __shared__ int partial[B];
    __shared__ int stage[CHUNK];

    int t = threadIdx.x, blk = blockIdx.x;
    for (int i = t; i < NBUCK; i += B) { lbase[i] = 0; cnt2[i] = 0; }
    __syncthreads();

    int eb = blk * CHUNK;
    int ds[PERT], ss[PERT];
#pragma unroll
    for (int k = 0; k < PERT; ++k) {
        int e = eb + k * B + t;
        ds[k] = dst[e];
        ss[k] = src[e];
        atomicAdd(&lbase[ds[k] >> 7], 1);
    }
    __syncthreads();

    int v0, v1, v2, v3;
    {
        int i0 = 4 * t;
        v0 = (i0 + 0 < NBUCK) ? lbase[i0 + 0] : 0;
        v1 = (i0 + 1 < NBUCK) ? lbase[i0 + 1] : 0;
        v2 = (i0 + 2 < NBUCK) ? lbase[i0 + 2] : 0;
        v3 = (i0 + 3 < NBUCK) ? lbase[i0 + 3] : 0;
        partial[t] = v0 + v1 + v2 + v3;
    }
    __syncthreads();
    for (int off = 1; off < B; off <<= 1) {
        int v = (t >= off) ? partial[t - off] : 0;
        __syncthreads();
        partial[t] += v;
        __syncthreads();
    }
    {
        int run = (t == 0) ? 0 : partial[t - 1];
        int i0 = 4 * t;
        if (i0 + 0 < NBUCK) lbase[i0 + 0] = run; run += v0;
        if (i0 + 1 < NBUCK) lbase[i0 + 1] = run; run += v1;
        if (i0 + 2 < NBUCK) lbase[i0 + 2] = run; run += v2;
        if (i0 + 3 < NBUCK) lbase[i0 + 3] = run;
    }
    for (int b = t; b < NBUCK; b += B)
        gb[b] = gbase(scanned, bsum, b * NBLK + blk);
    __syncthreads();

#pragma unroll
    for (int k = 0; k < PERT; ++k) {
        int d = ds[k], b = d >> 7;
        int r = atomicAdd(&cnt2[b], 1);
        stage[lbase[b] + r] = ss[k] | ((d & 127) << 17);
    }
    __syncthreads();

    int slot0 = t * PERT;
    int b = 0;
    for (int step = 512; step; step >>= 1) {
        int nb = b + step;
        if (nb < NBUCK && lbase[nb] <= slot0) b = nb;
    }
#pragma unroll
    for (int j = 0; j < PERT; ++j) {
        int slot = slot0 + j;
        while (b + 1 < NBUCK && lbase[b + 1] <= slot) ++b;
        packed[gb[b] + (slot - lbase[b])] = stage[slot];
    }
}

// ---- phase D1: per-bucket degree -> dis (int4 unrolled) ---------------------

__global__ void kD1_deg(const int* __restrict__ packed, const int* __restrict__ scanned,
                        const int* __restrict__ bsum, float* __restrict__ dis) {
    __shared__ int c[128];
    int t = threadIdx.x, b = blockIdx.x;
    if (t < 128) c[t] = 0;
    __syncthreads();
    int e0 = gbase(scanned, bsum, b * NBLK);
    int e1 = (b == NBUCK - 1) ? E : gbase(scanned, bsum, (b + 1) * NBLK);
    int a0 = (e0 + 3) & ~3; if (a0 > e1) a0 = e1;
    if (t < a0 - e0) atomicAdd(&c[packed[e0 + t] >> 17], 1);
    for (int base = a0; base < e1; base += 4 * B) {
        int e = base + 4 * t;
        int rem = e1 - e;
        if (rem >= 4) {
            int4 p4 = *(const int4*)(packed + e);
            atomicAdd(&c[p4.x >> 17], 1);
            atomicAdd(&c[p4.y >> 17], 1);
            atomicAdd(&c[p4.z >> 17], 1);
            atomicAdd(&c[p4.w >> 17], 1);
        } else if (rem > 0) {
            for (int k = 0; k < rem; ++k) atomicAdd(&c[packed[e + k] >> 17], 1);
        }
    }
    __syncthreads();
    int nbase = b * 128;
    int ncnt = min(128, N - nbase);
    if (t < ncnt) dis[nbase + t] = rsqrtf((float)(c[t] + 1));
}

// ---- phase D2: layer-1 aggregation (LDS acc, 4-edge ILP) + fused dense ------

__global__ void kD2_agg(const float* __restrict__ x, const float* __restrict__ dis,
                        const int* __restrict__ packed, const int* __restrict__ scanned,
                        const int* __restrict__ bsum,
                        const float* __restrict__ W1, const float* __restrict__ b1,
                        const float* __restrict__ W2, float* __restrict__ h2p) {
    __shared__ float acc[128 * 17];
    __shared__ float sW1[512], sb1[32], sW2[64], sdis[128];
    int t = threadIdx.x, b = blockIdx.x;
    for (int i = t; i < 512; i += B) sW1[i] = W1[i];
    if (t < 32) sb1[t] = b1[t];
    if (t < 64) sW2[t] = W2[t];

    int nbase = b * 128;
    int ncnt = min(128, N - nbase);
    const float4* x4 = (const float4*)x;
    if (t < 128) {
        float d = (t < ncnt) ? dis[nbase + t] : 0.f;
        sdis[t] = d;
        float d2 = d * d;
        float* row = acc + t * 17;
        if (t < ncnt) {
#pragma unroll
            for (int j = 0; j < 4; ++j) {
                float4 v = x4[(size_t)(nbase + t) * 4 + j];
                row[j * 4 + 0] = v.x * d2; row[j * 4 + 1] = v.y * d2;
                row[j * 4 + 2] = v.z * d2; row[j * 4 + 3] = v.w * d2;
            }
        }
    }
    __syncthreads();

    int e0 = gbase(scanned, bsum, b * NBLK);
    int e1 = (b == NBUCK - 1) ? E : gbase(scanned, bsum, (b + 1) * NBLK);

    // one-edge helper (prologue / ragged tail)
    auto one = [&](int e) {
        int p = packed[e];
        int s = p & 0x1FFFF;
        int lo = p >> 17;
        float nrm = dis[s] * sdis[lo];
        const float4* xp = x4 + (size_t)s * 4;
        float4 v0 = xp[0], v1 = xp[1], v2 = xp[2], v3 = xp[3];
        float* row = acc + lo * 17;
        atomicAdd(&row[0],  v0.x * nrm); atomicAdd(&row[1],  v0.y * nrm);
        atomicAdd(&row[2],  v0.z * nrm); atomicAdd(&row[3],  v0.w * nrm);
        atomicAdd(&row[4],  v1.x * nrm); atomicAdd(&row[5],  v1.y * nrm);
        atomicAdd(&row[6],  v1.z * nrm); atomicAdd(&row[7],  v1.w * nrm);
        atomicAdd(&row[8],  v2.x * nrm); atomicAdd(&row[9],  v2.y * nrm);
        atomicAdd(&row[10], v2.z * nrm); atomicAdd(&row[11], v2.w * nrm);
        atomicAdd(&row[12], v3.x * nrm); atomicAdd(&row[13], v3.y * nrm);
        atomicAdd(&row[14], v3.z * nrm); atomicAdd(&row[15], v3.w * nrm);
    };

    int a0 = (e0 + 3) & ~3; if (a0 > e1) a0 = e1;
    if (t < a0 - e0) one(e0 + t);

    for (int base = a0; base < e1; base += 4 * B) {
        int e = base + 4 * t;
        int rem = e1 - e;
        if (rem >= 4) {
            int4 p4 = *(const int4*)(packed + e);
            int s0 = p4.x & 0x1FFFF, l0 = p4.x >> 17;
            int s1 = p4.y & 0x1FFFF, l1 = p4.y >> 17;
            int s2 = p4.z & 0x1FFFF, l2 = p4.z >> 17;
            int s3 = p4.w & 0x1FFFF, l3 = p4.w >> 17;
            float n0 = dis[s0] * sdis[l0];
            float n1 = dis[s1] * sdis[l1];
            float n2 = dis[s2] * sdis[l2];
            float n3 = dis[s3] * sdis[l3];
            const float4* p0 = x4 + (size_t)s0 * 4;
            const float4* p1 = x4 + (size_t)s1 * 4;
            const float4* p2 = x4 + (size_t)s2 * 4;
            const float4* p3 = x4 + (size_t)s3 * 4;
            float4 a00 = p0[0], a01 = p0[1], a02 = p0[2], a03 = p0[3];
            float4 a10 = p1[0], a11 = p1[1], a12 = p1[2], a13 = p1[3];
            float4 a20 = p2[0], a21 = p2[1], a22 = p2[2], a23 = p2[3];
            float4 a30 = p3[0], a31 = p3[1], a32 = p3[2], a33 = p3[3];
            float* r0 = acc + l0 * 17;
            float* r1 = acc + l1 * 17;
            float* r2 = acc + l2 * 17;
            float* r3 = acc + l3 * 17;
            atomicAdd(&r0[0], a00.x*n0); atomicAdd(&r0[1], a00.y*n0); atomicAdd(&r0[2], a00.z*n0); atomicAdd(&r0[3], a00.w*n0);
            atomicAdd(&r0[4], a01.x*n0); atomicAdd(&r0[5], a01.y*n0); atomicAdd(&r0[6], a01.z*n0); atomicAdd(&r0[7], a01.w*n0);
            atomicAdd(&r0[8], a02.x*n0); atomicAdd(&r0[9], a02.y*n0); atomicAdd(&r0[10],a02.z*n0); atomicAdd(&r0[11],a02.w*n0);
            atomicAdd(&r0[12],a03.x*n0); atomicAdd(&r0[13],a03.y*n0); atomicAdd(&r0[14],a03.z*n0); atomicAdd(&r0[15],a03.w*n0);
            atomicAdd(&r1[0], a10.x*n1); atomicAdd(&r1[1], a10.y*n1); atomicAdd(&r1[2], a10.z*n1); atomicAdd(&r1[3], a10.w*n1);
            atomicAdd(&r1[4], a11.x*n1); atomicAdd(&r1[5], a11.y*n1); atomicAdd(&r1[6], a11.z*n1); atomicAdd(&r1[7], a11.w*n1);
            atomicAdd(&r1[8], a12.x*n1); atomicAdd(&r1[9], a12.y*n1); atomicAdd(&r1[10],a12.z*n1); atomicAdd(&r1[11],a12.w*n1);
            atomicAdd(&r1[12],a13.x*n1); atomicAdd(&r1[13],a13.y*n1); atomicAdd(&r1[14],a13.z*n1); atomicAdd(&r1[15],a13.w*n1);
            atomicAdd(&r2[0], a20.x*n2); atomicAdd(&r2[1], a20.y*n2); atomicAdd(&r2[2], a20.z*n2); atomicAdd(&r2[3], a20.w*n2);
            atomicAdd(&r2[4], a21.x*n2); atomicAdd(&r2[5], a21.y*n2); atomicAdd(&r2[6], a21.z*n2); atomicAdd(&r2[7], a21.w*n2);
            atomicAdd(&r2[8], a22.x*n2); atomicAdd(&r2[9], a22.y*n2); atomicAdd(&r2[10],a22.z*n2); atomicAdd(&r2[11],a22.w*n2);
            atomicAdd(&r2[12],a23.x*n2); atomicAdd(&r2[13],a23.y*n2); atomicAdd(&r2[14],a23.z*n2); atomicAdd(&r2[15],a23.w*n2);
            atomicAdd(&r3[0], a30.x*n3); atomicAdd(&r3[1], a30.y*n3); atomicAdd(&r3[2], a30.z*n3); atomicAdd(&r3[3], a30.w*n3);
            atomicAdd(&r3[4], a31.x*n3); atomicAdd(&r3[5], a31.y*n3); atomicAdd(&r3[6], a31.z*n3); atomicAdd(&r3[7], a31.w*n3);
            atomicAdd(&r3[8], a32.x*n3); atomicAdd(&r3[9], a32.y*n3); atomicAdd(&r3[10],a32.z*n3); atomicAdd(&r3[11],a32.w*n3);
            atomicAdd(&r3[12],a33.x*n3); atomicAdd(&r3[13],a33.y*n3); atomicAdd(&r3[14],a33.z*n3); atomicAdd(&r3[15],a33.w*n3);
        } else if (rem > 0) {
            for (int k = 0; k < rem; ++k) one(e + k);
        }
    }
    __syncthreads();

    if (t < ncnt) {
        const float* row = acc + t * 17;
        float xi[16];
#pragma unroll
        for (int k = 0; k < 16; ++k) xi[k] = row[k];
        float o0 = 0.f, o1 = 0.f;
#pragma unroll
        for (int c = 0; c < 32; ++c) {
            float h = sb1[c];
#pragma unroll
            for (int k = 0; k < 16; ++k) h = fmaf(xi[k], sW1[k * 32 + c], h);
            h = fmaxf(h, 0.f);
            o0 = fmaf(h, sW2[c * 2 + 0], o0);
            o1 = fmaf(h, sW2[c * 2 + 1], o1);
        }
        ((float2*)h2p)[nbase + t] = make_float2(o0, o1);
    }
}

// ---- phase F: layer-2 aggregation (4-edge ILP) + bias -----------------------

__global__ void kF_l2(const float* __restrict__ h2p, const float* __restrict__ dis,
                      const int* __restrict__ packed, const int* __restrict__ scanned,
                      const int* __restrict__ bsum, const float* __restrict__ b2,
                      float* __restrict__ out) {
    __shared__ float a2[128 * 2];
    __shared__ float sdis[128];
    int t = threadIdx.x, b = blockIdx.x;
    int nbase = b * 128;
    int ncnt = min(128, N - nbase);
    const float2* h2 = (const float2*)h2p;
    if (t < 128) {
        float d = (t < ncnt) ? dis[nbase + t] : 0.f;
        sdis[t] = d;
        if (t < ncnt) {
            float d2 = d * d;
            float2 hv = h2[nbase + t];
            a2[t * 2 + 0] = fmaf(hv.x, d2, b2[0]);
            a2[t * 2 + 1] = fmaf(hv.y, d2, b2[1]);
        }
    }
    __syncthreads();
    int e0 = gbase(scanned, bsum, b * NBLK);
    int e1 = (b == NBUCK - 1) ? E : gbase(scanned, bsum, (b + 1) * NBLK);

    auto one = [&](int e) {
        int p = packed[e];
        int s = p & 0x1FFFF;
        int lo = p >> 17;
        float nrm = dis[s] * sdis[lo];
        float2 v = h2[s];
        atomicAdd(&a2[lo * 2 + 0], v.x * nrm);
        atomicAdd(&a2[lo * 2 + 1], v.y * nrm);
    };

    int a0 = (e0 + 3) & ~3; if (a0 > e1) a0 = e1;
    if (t < a0 - e0) one(e0 + t);

    for (int base = a0; base < e1; base += 4 * B) {
        int e = base + 4 * t;
        int rem = e1 - e;
        if (rem >= 4) {
            int4 p4 = *(const int4*)(packed + e);
            int s0 = p4.x & 0x1FFFF, l0 = p4.x >> 17;
            int s1 = p4.y & 0x1FFFF, l1 = p4.y >> 17;
            int s2 = p4.z & 0x1FFFF, l2 = p4.z >> 17;
            int s3 = p4.w & 0x1FFFF, l3 = p4.w >> 17;
            float n0 = dis[s0] * sdis[l0];
            float n1 = dis[s1] * sdis[l1];
            float n2 = dis[s2] * sdis[l2];
            float n3 = dis[s3] * sdis[l3];
            float2 v0 = h2[s0], v1 = h2[s1], v2 = h2[s2], v3 = h2[s3];
            atomicAdd(&a2[l0 * 2 + 0], v0.x * n0); atomicAdd(&a2[l0 * 2 + 1], v0.y * n0);
            atomicAdd(&a2[l1 * 2 + 0], v1.x * n1); atomicAdd(&a2[l1 * 2 + 1], v1.y * n1);
            atomicAdd(&a2[l2 * 2 + 0], v2.x * n2); atomicAdd(&a2[l2 * 2 + 1], v2.y * n2);
            atomicAdd(&a2[l3 * 2 + 0], v3.x * n3); atomicAdd(&a2[l3 * 2 + 1], v3.y * n3);
        } else if (rem > 0) {
            for (int k = 0; k < rem; ++k) one(e + k);
        }
    }
    __syncthreads();
    if (t < ncnt)
        ((float2*)out)[nbase + t] = make_float2(a2[t * 2], a2[t * 2 + 1]);
}

// ---- launcher ---------------------------------------------------------------

extern "C" void kernel_launch(void* const* d_in, const int* in_sizes, int n_in,
                              void* d_out, int out_size, void* d_ws, size_t ws_size,
                              hipStream_t stream) {
    const float* x  = (const float*)d_in[0];
    const int*   ei = (const int*)d_in[1];
    const float* W1 = (const float*)d_in[2];
    const float* b1 = (const float*)d_in[3];
    const float* W2 = (const float*)d_in[4];
    const float* b2 = (const float*)d_in[5];
    float* out = (float*)d_out;

    const int* src = ei;
    const int* dst = ei + E;

    int*   packed  = (int*)d_ws;                       // E
    int*   counts  = packed + E;                       // NSB*B
    int*   scanned = counts + NSB * B;                 // NSB*B
    int*   bsum    = scanned + NSB * B;                // 1024
    float* dis     = (float*)(bsum + 1024);            // N
    float* h2p     = dis + N;                          // 2N

    kA_hist<<<NBLK, B, 0, stream>>>(dst, counts);
    ks1<<<NSB, B, 0, stream>>>(counts, scanned, bsum);
    ks2<<<1, 1024, 0, stream>>>(bsum);
    kC_scatter<<<NBLK, B, 0, stream>>>(src, dst, scanned, bsum, packed);
    kD1_deg<<<NBUCK, B, 0, stream>>>(packed, scanned, bsum, dis);
    kD2_agg<<<NBUCK, B, 0, stream>>>(x, dis, packed, scanned, bsum, W1, b1, W2, h2p);
    kF_l2<<<NBUCK, B, 0, stream>>>(h2p, dis, packed, scanned, bsum, b2, out);
}

// Round 6
// 296.066 us; speedup vs baseline: 1.0602x; 1.0602x over previous
//
#include <hip/hip_runtime.h>

static constexpr int N  = 100000;
static constexpr int E  = 1600000;
static constexpr int B  = 256;

static constexpr int NBLK  = 250;                  // partition blocks
static constexpr int CHUNK = E / NBLK;             // 6400 edges per block
static constexpr int PERT  = CHUNK / B;            // 25 edges per thread
static constexpr int NBUCK = (N + 63) / 64;        // 1563 buckets of 64 nodes
static constexpr int NCNT  = NBUCK * NBLK;         // 390750
static constexpr int NSB   = (NCNT + B - 1) / B;   // 1527 scan blocks

__device__ __forceinline__ int gbase(const int* scanned, const int* bsum, int idx) {
    return scanned[idx] + bsum[idx >> 8];
}

__device__ __forceinline__ void lds_fadd(float* p, float v) {
    __hip_atomic_fetch_add(p, v, __ATOMIC_RELAXED, __HIP_MEMORY_SCOPE_WORKGROUP);
}

// ---- phase A: per-block bucket histogram ------------------------------------

__global__ void kA_hist(const int* __restrict__ dst, int* __restrict__ counts) {
    __shared__ int hist[NBUCK];
    int t = threadIdx.x, blk = blockIdx.x;
    for (int i = t; i < NBUCK; i += B) hist[i] = 0;
    __syncthreads();
    int eb = blk * CHUNK;
#pragma unroll
    for (int k = 0; k < PERT; ++k) {
        int d = dst[eb + k * B + t];
        atomicAdd(&hist[d >> 6], 1);
    }
    __syncthreads();
    for (int b = t; b < NBUCK; b += B) counts[b * NBLK + blk] = hist[b];
}

// ---- scan -------------------------------------------------------------------

__global__ void ks1(const int* __restrict__ counts, int* __restrict__ scanned,
                    int* __restrict__ bsum) {
    __shared__ int s[B];
    int t = threadIdx.x;
    int g = blockIdx.x * B + t;
    s[t] = (g < NCNT) ? counts[g] : 0;
    __syncthreads();
    for (int off = 1; off < B; off <<= 1) {
        int v = (t >= off) ? s[t - off] : 0;
        __syncthreads();
        s[t] += v;
        __syncthreads();
    }
    if (g < NCNT) scanned[g] = (t == 0) ? 0 : s[t - 1];
    if (t == B - 1) bsum[blockIdx.x] = s[t];
}

// chunked serial scan of NSB block sums (NSB may exceed 1024)
__global__ void ks2(int* __restrict__ bsum) {
    __shared__ int s[1024];
    __shared__ int carry_s;
    int t = threadIdx.x;
    if (t == 0) carry_s = 0;
    __syncthreads();
    for (int base = 0; base < NSB; base += 1024) {
        int idx = base + t;
        s[t] = (idx < NSB) ? bsum[idx] : 0;
        __syncthreads();
        for (int off = 1; off < 1024; off <<= 1) {
            int u = (t >= off) ? s[t - off] : 0;
            __syncthreads();
            s[t] += u;
            __syncthreads();
        }
        int carry = carry_s;
        __syncthreads();
        if (idx < NSB) bsum[idx] = carry + ((t == 0) ? 0 : s[t - 1]);
        if (t == 1023) carry_s = carry + s[1023];
        __syncthreads();
    }
}

// ---- phase C: stable partition with LDS staging -----------------------------

__global__ void kC_scatter(const int* __restrict__ src, const int* __restrict__ dst,
                           const int* __restrict__ scanned, const int* __restrict__ bsum,
                           int* __restrict__ packed) {
    __shared__ int lbase[NBUCK];
    __shared__ int cnt2[NBUCK];
    __shared__ int gb[NBUCK];
    __shared__ int partial[B];
    __shared__ int stage[CHUNK];

    int t = threadIdx.x, blk = blockIdx.x;
    for (int i = t; i < NBUCK; i += B) { lbase[i] = 0; cnt2[i] = 0; }
    __syncthreads();

    int eb = blk * CHUNK;
    int ds[PERT], ss[PERT];
#pragma unroll
    for (int k = 0; k < PERT; ++k) {
        int e = eb + k * B + t;
        ds[k] = dst[e];
        ss[k] = src[e];
        atomicAdd(&lbase[ds[k] >> 6], 1);
    }
    __syncthreads();

    // exclusive scan of lbase[0..NBUCK): 8 elems/thread blocked + HS over partials
    int v[8];
    {
        int i0 = 8 * t, sum = 0;
#pragma unroll
        for (int k = 0; k < 8; ++k) {
            v[k] = (i0 + k < NBUCK) ? lbase[i0 + k] : 0;
            sum += v[k];
        }
        partial[t] = sum;
    }
    __syncthreads();
    for (int off = 1; off < B; off <<= 1) {
        int u = (t >= off) ? partial[t - off] : 0;
        __syncthreads();
        partial[t] += u;
        __syncthreads();
    }
    {
        int run = (t == 0) ? 0 : partial[t - 1];
        int i0 = 8 * t;
#pragma unroll
        for (int k = 0; k < 8; ++k) {
            if (i0 + k < NBUCK) lbase[i0 + k] = run;
            run += v[k];
        }
    }
    for (int b = t; b < NBUCK; b += B)
        gb[b] = gbase(scanned, bsum, b * NBLK + blk);
    __syncthreads();

    // place into LDS stage, packed as (dst&63)<<17 | src
#pragma unroll
    for (int k = 0; k < PERT; ++k) {
        int d = ds[k], b = d >> 6;
        int r = atomicAdd(&cnt2[b], 1);
        stage[lbase[b] + r] = ss[k] | ((d & 63) << 17);
    }
    __syncthreads();

    // interleaved write-out: consecutive lanes -> consecutive slots -> coalesced runs
    for (int slot = t; slot < CHUNK; slot += B) {
        int b = 0;
        for (int step = 1024; step; step >>= 1) {
            int nb = b + step;
            if (nb < NBUCK && lbase[nb] <= slot) b = nb;
        }
        packed[gb[b] + (slot - lbase[b])] = stage[slot];
    }
}

// ---- phase D1: per-bucket degree -> dis, and x_pre = dis * x ----------------

__global__ void kD1_deg(const int* __restrict__ packed, const int* __restrict__ scanned,
                        const int* __restrict__ bsum, const float4* __restrict__ x4,
                        float* __restrict__ dis, float4* __restrict__ xpre4) {
    __shared__ int c[64];
    int t = threadIdx.x, b = blockIdx.x;
    if (t < 64) c[t] = 0;
    __syncthreads();
    int e0 = gbase(scanned, bsum, b * NBLK);
    int e1 = (b == NBUCK - 1) ? E : gbase(scanned, bsum, (b + 1) * NBLK);
    int a0 = (e0 + 3) & ~3; if (a0 > e1) a0 = e1;
    if (e0 + t < a0) atomicAdd(&c[packed[e0 + t] >> 17], 1);
    for (int e = a0 + 4 * t; e < e1; e += 4 * B) {
        int rem = e1 - e;
        if (rem >= 4) {
            int4 p4 = *(const int4*)(packed + e);
            atomicAdd(&c[p4.x >> 17], 1);
            atomicAdd(&c[p4.y >> 17], 1);
            atomicAdd(&c[p4.z >> 17], 1);
            atomicAdd(&c[p4.w >> 17], 1);
        } else {
            for (int k = 0; k < rem; ++k) atomicAdd(&c[packed[e + k] >> 17], 1);
        }
    }
    __syncthreads();
    int nbase = b * 64;
    int ncnt = min(64, N - nbase);
    if (t < ncnt) dis[nbase + t] = rsqrtf((float)(c[t] + 1));
    // x_pre rows for this bucket: 64 nodes x 4 quads = 256 lane-slots
    {
        int n = t >> 2, j = t & 3;
        if (n < ncnt) {
            float d = rsqrtf((float)(c[n] + 1));
            float4 vv = x4[(size_t)(nbase + n) * 4 + j];
            vv.x *= d; vv.y *= d; vv.z *= d; vv.w *= d;
            xpre4[(size_t)(nbase + n) * 4 + j] = vv;
        }
    }
}

// ---- phase D2: layer-1 aggregation (4 lanes/edge) + fused dense -------------

__global__ void kD2_agg(const float4* __restrict__ xpre4, const float* __restrict__ dis,
                        const int* __restrict__ packed, const int* __restrict__ scanned,
                        const int* __restrict__ bsum, const float* __restrict__ W1,
                        const float* __restrict__ b1, const float* __restrict__ W2,
                        float2* __restrict__ hpre) {
    __shared__ float acc[64 * 17];
    __shared__ float sW1[512], sb1[32], sW2[64];
    int t = threadIdx.x, b = blockIdx.x;
    for (int i = t; i < 512; i += B) sW1[i] = W1[i];
    if (t < 32) sb1[t] = b1[t];
    if (t < 64) sW2[t] = W2[t];

    int nbase = b * 64;
    int ncnt = min(64, N - nbase);
    {   // self-loop init: acc row n = x_pre[nbase+n]
        int n = t >> 2, j = t & 3;
        if (n < ncnt) {
            float4 vv = xpre4[(size_t)(nbase + n) * 4 + j];
            float* r = acc + n * 17 + j * 4;
            r[0] = vv.x; r[1] = vv.y; r[2] = vv.z; r[3] = vv.w;
        }
    }
    __syncthreads();

    int e0 = gbase(scanned, bsum, b * NBLK);
    int e1 = (b == NBUCK - 1) ? E : gbase(scanned, bsum, (b + 1) * NBLK);
    int nE = e1 - e0;
    int j = t & 3;            // fixed channel-quad per thread
    int idx = t >> 2;         // edge slot, strides by 64

    // 4-deep pipeline: 4 edges in flight, 5 VGPRs each
    for (; idx + 192 < nE; idx += 256) {
        int p0 = packed[e0 + idx];
        int p1 = packed[e0 + idx + 64];
        int p2 = packed[e0 + idx + 128];
        int p3 = packed[e0 + idx + 192];
        float4 v0 = xpre4[(size_t)(p0 & 0x1FFFF) * 4 + j];
        float4 v1 = xpre4[(size_t)(p1 & 0x1FFFF) * 4 + j];
        float4 v2 = xpre4[(size_t)(p2 & 0x1FFFF) * 4 + j];
        float4 v3 = xpre4[(size_t)(p3 & 0x1FFFF) * 4 + j];
        float* r0 = acc + (p0 >> 17) * 17 + j * 4;
        float* r1 = acc + (p1 >> 17) * 17 + j * 4;
        float* r2 = acc + (p2 >> 17) * 17 + j * 4;
        float* r3 = acc + (p3 >> 17) * 17 + j * 4;
        lds_fadd(r0 + 0, v0.x); lds_fadd(r0 + 1, v0.y); lds_fadd(r0 + 2, v0.z); lds_fadd(r0 + 3, v0.w);
        lds_fadd(r1 + 0, v1.x); lds_fadd(r1 + 1, v1.y); lds_fadd(r1 + 2, v1.z); lds_fadd(r1 + 3, v1.w);
        lds_fadd(r2 + 0, v2.x); lds_fadd(r2 + 1, v2.y); lds_fadd(r2 + 2, v2.z); lds_fadd(r2 + 3, v2.w);
        lds_fadd(r3 + 0, v3.x); lds_fadd(r3 + 1, v3.y); lds_fadd(r3 + 2, v3.z); lds_fadd(r3 + 3, v3.w);
    }
    for (; idx < nE; idx += 64) {
        int p = packed[e0 + idx];
        float4 vv = xpre4[(size_t)(p & 0x1FFFF) * 4 + j];
        float* r = acc + (p >> 17) * 17 + j * 4;
        lds_fadd(r + 0, vv.x); lds_fadd(r + 1, vv.y); lds_fadd(r + 2, vv.z); lds_fadd(r + 3, vv.w);
    }
    __syncthreads();

    // epilogue: acc1 = dis[d] * rowsum; h = relu(acc1 @ W1 + b1); hpre = dis[d] * (h @ W2)
    if (t < ncnt) {
        float d = dis[nbase + t];
        const float* row = acc + t * 17;
        float xi[16];
#pragma unroll
        for (int k = 0; k < 16; ++k) xi[k] = row[k] * d;
        float o0 = 0.f, o1 = 0.f;
#pragma unroll
        for (int c = 0; c < 32; ++c) {
            float h = sb1[c];
#pragma unroll
            for (int k = 0; k < 16; ++k) h = fmaf(xi[k], sW1[k * 32 + c], h);
            h = fmaxf(h, 0.f);
            o0 = fmaf(h, sW2[c * 2 + 0], o0);
            o1 = fmaf(h, sW2[c * 2 + 1], o1);
        }
        hpre[nbase + t] = make_float2(d * o0, d * o1);
    }
}

// ---- phase F: layer-2 aggregation (2 lanes/edge) + bias ---------------------

__global__ void kF_l2(const float* __restrict__ hpre, const float* __restrict__ dis,
                      const int* __restrict__ packed, const int* __restrict__ scanned,
                      const int* __restrict__ bsum, const float* __restrict__ b2,
                      float2* __restrict__ out) {
    __shared__ float a2[64 * 3];     // stride-3 pad for bank spread
    int t = threadIdx.x, b = blockIdx.x;
    int nbase = b * 64;
    int ncnt = min(64, N - nbase);
    {   // self-loop init
        int n = t >> 1, jj = t & 1;
        if (t < 128 && n < ncnt) a2[n * 3 + jj] = hpre[(size_t)(nbase + n) * 2 + jj];
    }
    __syncthreads();
    int e0 = gbase(scanned, bsum, b * NBLK);
    int e1 = (b == NBUCK - 1) ? E : gbase(scanned, bsum, (b + 1) * NBLK);
    int nE = e1 - e0;
    int j = t & 1;
    int idx = t >> 1;        // strides by 128
    for (; idx + 384 < nE; idx += 512) {
        int p0 = packed[e0 + idx];
        int p1 = packed[e0 + idx + 128];
        int p2 = packed[e0 + idx + 256];
        int p3 = packed[e0 + idx + 384];
        float v0 = hpre[(size_t)(p0 & 0x1FFFF) * 2 + j];
        float v1 = hpre[(size_t)(p1 & 0x1FFFF) * 2 + j];
        float v2 = hpre[(size_t)(p2 & 0x1FFFF) * 2 + j];
        float v3 = hpre[(size_t)(p3 & 0x1FFFF) * 2 + j];
        lds_fadd(&a2[(p0 >> 17) * 3 + j], v0);
        lds_fadd(&a2[(p1 >> 17) * 3 + j], v1);
        lds_fadd(&a2[(p2 >> 17) * 3 + j], v2);
        lds_fadd(&a2[(p3 >> 17) * 3 + j], v3);
    }
    for (; idx < nE; idx += 128) {
        int p = packed[e0 + idx];
        float vv = hpre[(size_t)(p & 0x1FFFF) * 2 + j];
        lds_fadd(&a2[(p >> 17) * 3 + j], vv);
    }
    __syncthreads();
    if (t < ncnt) {
        float d = dis[nbase + t];
        out[nbase + t] = make_float2(fmaf(d, a2[t * 3 + 0], b2[0]),
                                     fmaf(d, a2[t * 3 + 1], b2[1]));
    }
}

// ---- launcher ---------------------------------------------------------------

extern "C" void kernel_launch(void* const* d_in, const int* in_sizes, int n_in,
                              void* d_out, int out_size, void* d_ws, size_t ws_size,
                              hipStream_t stream) {
    const float* x  = (const float*)d_in[0];
    const int*   ei = (const int*)d_in[1];
    const float* W1 = (const float*)d_in[2];
    const float* b1 = (const float*)d_in[3];
    const float* W2 = (const float*)d_in[4];
    const float* b2 = (const float*)d_in[5];

    const int* src = ei;
    const int* dst = ei + E;

    // workspace layout (ints/floats are 4 B; keep 64 B alignment for xpre)
    int*   packed  = (int*)d_ws;                       // E
    int*   counts  = packed + E;                       // NSB*B
    int*   scanned = counts + (size_t)NSB * B;         // NSB*B
    int*   bsum    = scanned + (size_t)NSB * B;        // 2048
    float* dis     = (float*)(bsum + 2048);            // N
    float* xpre    = dis + N;                          // 16N (64 B aligned)
    float* hpre    = xpre + (size_t)N * 16;            // 2N

    kA_hist<<<NBLK, B, 0, stream>>>(dst, counts);
    ks1<<<NSB, B, 0, stream>>>(counts, scanned, bsum);
    ks2<<<1, 1024, 0, stream>>>(bsum);
    kC_scatter<<<NBLK, B, 0, stream>>>(src, dst, scanned, bsum, packed);
    kD1_deg<<<NBUCK, B, 0, stream>>>(packed, scanned, bsum, (const float4*)x, dis,
                                     (float4*)xpre);
    kD2_agg<<<NBUCK, B, 0, stream>>>((const float4*)xpre, dis, packed, scanned, bsum,
                                     W1, b1, W2, (float2*)hpre);
    kF_l2<<<NBUCK, B, 0, stream>>>(hpre, dis, packed, scanned, bsum, b2,
                                   (float2*)d_out);
}

// Round 7
// 295.432 us; speedup vs baseline: 1.0624x; 1.0021x over previous
//
#include <hip/hip_runtime.h>
#include <hip/hip_fp16.h>

static constexpr int N  = 100000;
static constexpr int E  = 1600000;
static constexpr int B  = 256;

static constexpr int NBLK  = 250;                  // partition blocks
static constexpr int CHUNK = E / NBLK;             // 6400 edges per block
static constexpr int PERT  = CHUNK / B;            // 25 edges per thread
static constexpr int NBUCK = (N + 63) / 64;        // 1563 buckets of 64 nodes
static constexpr int NCNT  = NBUCK * NBLK;         // 390750
static constexpr int NSB   = (NCNT + B - 1) / B;   // 1527 scan blocks

__device__ __forceinline__ int gbase(const int* scanned, const int* bsum, int idx) {
    return scanned[idx] + bsum[idx >> 8];
}

__device__ __forceinline__ void lds_fadd(float* p, float v) {
    __hip_atomic_fetch_add(p, v, __ATOMIC_RELAXED, __HIP_MEMORY_SCOPE_WORKGROUP);
}

// ---- phase A: per-block bucket histogram ------------------------------------

__global__ void kA_hist(const int* __restrict__ dst, int* __restrict__ counts) {
    __shared__ int hist[NBUCK];
    int t = threadIdx.x, blk = blockIdx.x;
    for (int i = t; i < NBUCK; i += B) hist[i] = 0;
    __syncthreads();
    int eb = blk * CHUNK;
#pragma unroll
    for (int k = 0; k < PERT; ++k) {
        int d = dst[eb + k * B + t];
        atomicAdd(&hist[d >> 6], 1);
    }
    __syncthreads();
    for (int b = t; b < NBUCK; b += B) counts[b * NBLK + blk] = hist[b];
}

// ---- scan -------------------------------------------------------------------

__global__ void ks1(const int* __restrict__ counts, int* __restrict__ scanned,
                    int* __restrict__ bsum) {
    __shared__ int s[B];
    int t = threadIdx.x;
    int g = blockIdx.x * B + t;
    s[t] = (g < NCNT) ? counts[g] : 0;
    __syncthreads();
    for (int off = 1; off < B; off <<= 1) {
        int v = (t >= off) ? s[t - off] : 0;
        __syncthreads();
        s[t] += v;
        __syncthreads();
    }
    if (g < NCNT) scanned[g] = (t == 0) ? 0 : s[t - 1];
    if (t == B - 1) bsum[blockIdx.x] = s[t];
}

__global__ void ks2(int* __restrict__ bsum) {
    __shared__ int s[1024];
    __shared__ int carry_s;
    int t = threadIdx.x;
    if (t == 0) carry_s = 0;
    __syncthreads();
    for (int base = 0; base < NSB; base += 1024) {
        int idx = base + t;
        s[t] = (idx < NSB) ? bsum[idx] : 0;
        __syncthreads();
        for (int off = 1; off < 1024; off <<= 1) {
            int u = (t >= off) ? s[t - off] : 0;
            __syncthreads();
            s[t] += u;
            __syncthreads();
        }
        int carry = carry_s;
        __syncthreads();
        if (idx < NSB) bsum[idx] = carry + ((t == 0) ? 0 : s[t - 1]);
        if (t == 1023) carry_s = carry + s[1023];
        __syncthreads();
    }
}

// ---- phase C: stable partition with LDS staging -----------------------------

__global__ void kC_scatter(const int* __restrict__ src, const int* __restrict__ dst,
                           const int* __restrict__ scanned, const int* __restrict__ bsum,
                           int* __restrict__ packed) {
    __shared__ int lbase[NBUCK];
    __shared__ int cnt2[NBUCK];
    __shared__ int gb[NBUCK];
    __shared__ int partial[B];
    __shared__ int stage[CHUNK];

    int t = threadIdx.x, blk = blockIdx.x;
    for (int i = t; i < NBUCK; i += B) { lbase[i] = 0; cnt2[i] = 0; }
    __syncthreads();

    int eb = blk * CHUNK;
    int ds[PERT], ss[PERT];
#pragma unroll
    for (int k = 0; k < PERT; ++k) {
        int e = eb + k * B + t;
        ds[k] = dst[e];
        ss[k] = src[e];
        atomicAdd(&lbase[ds[k] >> 6], 1);
    }
    __syncthreads();

    int v[8];
    {
        int i0 = 8 * t, sum = 0;
#pragma unroll
        for (int k = 0; k < 8; ++k) {
            v[k] = (i0 + k < NBUCK) ? lbase[i0 + k] : 0;
            sum += v[k];
        }
        partial[t] = sum;
    }
    __syncthreads();
    for (int off = 1; off < B; off <<= 1) {
        int u = (t >= off) ? partial[t - off] : 0;
        __syncthreads();
        partial[t] += u;
        __syncthreads();
    }
    {
        int run = (t == 0) ? 0 : partial[t - 1];
        int i0 = 8 * t;
#pragma unroll
        for (int k = 0; k < 8; ++k) {
            if (i0 + k < NBUCK) lbase[i0 + k] = run;
            run += v[k];
        }
    }
    for (int b = t; b < NBUCK; b += B)
        gb[b] = gbase(scanned, bsum, b * NBLK + blk);
    __syncthreads();

#pragma unroll
    for (int k = 0; k < PERT; ++k) {
        int d = ds[k], b = d >> 6;
        int r = atomicAdd(&cnt2[b], 1);
        stage[lbase[b] + r] = ss[k] | ((d & 63) << 17);
    }
    __syncthreads();

    for (int slot = t; slot < CHUNK; slot += B) {
        int b = 0;
        for (int step = 1024; step; step >>= 1) {
            int nb = b + step;
            if (nb < NBUCK && lbase[nb] <= slot) b = nb;
        }
        packed[gb[b] + (slot - lbase[b])] = stage[slot];
    }
}

// ---- phase D1: per-bucket degree -> dis, and x_pre = (half) dis * x ---------

__global__ void kD1_deg(const int* __restrict__ packed, const int* __restrict__ scanned,
                        const int* __restrict__ bsum, const float4* __restrict__ x4,
                        float* __restrict__ dis, __half* __restrict__ xpre) {
    __shared__ int c[64];
    int t = threadIdx.x, b = blockIdx.x;
    if (t < 64) c[t] = 0;
    __syncthreads();
    int e0 = gbase(scanned, bsum, b * NBLK);
    int e1 = (b == NBUCK - 1) ? E : gbase(scanned, bsum, (b + 1) * NBLK);
    int a0 = (e0 + 3) & ~3; if (a0 > e1) a0 = e1;
    if (e0 + t < a0) atomicAdd(&c[packed[e0 + t] >> 17], 1);
    for (int e = a0 + 4 * t; e < e1; e += 4 * B) {
        int rem = e1 - e;
        if (rem >= 4) {
            int4 p4 = *(const int4*)(packed + e);
            atomicAdd(&c[p4.x >> 17], 1);
            atomicAdd(&c[p4.y >> 17], 1);
            atomicAdd(&c[p4.z >> 17], 1);
            atomicAdd(&c[p4.w >> 17], 1);
        } else {
            for (int k = 0; k < rem; ++k) atomicAdd(&c[packed[e + k] >> 17], 1);
        }
    }
    __syncthreads();
    int nbase = b * 64;
    int ncnt = min(64, N - nbase);
    if (t < ncnt) dis[nbase + t] = rsqrtf((float)(c[t] + 1));
    {   // xpre rows: 64 nodes x 4 quads; each lane converts 4 floats -> 4 halfs
        int n = t >> 2, j = t & 3;
        if (n < ncnt) {
            float d = rsqrtf((float)(c[n] + 1));
            float4 vv = x4[(size_t)(nbase + n) * 4 + j];
            ushort4 pk;
            pk.x = __half_as_ushort(__float2half(vv.x * d));
            pk.y = __half_as_ushort(__float2half(vv.y * d));
            pk.z = __half_as_ushort(__float2half(vv.z * d));
            pk.w = __half_as_ushort(__float2half(vv.w * d));
            *(ushort4*)(xpre + (size_t)(nbase + n) * 16 + j * 4) = pk;
        }
    }
}

// ---- phase D2: layer-1 aggregation (2 lanes/edge, fp16 table) + dense -------

__global__ void kD2_agg(const __half* __restrict__ xpre, const float* __restrict__ dis,
                        const int* __restrict__ packed, const int* __restrict__ scanned,
                        const int* __restrict__ bsum, const float* __restrict__ W1,
                        const float* __restrict__ b1, const float* __restrict__ W2,
                        float2* __restrict__ hpre) {
    __shared__ float acc[64 * 17];
    __shared__ float sW1[512], sb1[32], sW2[64];
    int t = threadIdx.x, b = blockIdx.x;
    for (int i = t; i < 512; i += B) sW1[i] = W1[i];
    if (t < 32) sb1[t] = b1[t];
    if (t < 64) sW2[t] = W2[t];

    int nbase = b * 64;
    int ncnt = min(64, N - nbase);
    {   // self-loop init from fp16 table (consistent rounding)
        int n = t >> 1, j = t & 1;
        if (t < 128 && n < ncnt) {
            int4 w = *(const int4*)(xpre + (size_t)(nbase + n) * 16 + j * 8);
            float2 c0 = __half22float2(*(__half2*)&w.x);
            float2 c1 = __half22float2(*(__half2*)&w.y);
            float2 c2 = __half22float2(*(__half2*)&w.z);
            float2 c3 = __half22float2(*(__half2*)&w.w);
            float* r = acc + n * 17 + j * 8;
            r[0] = c0.x; r[1] = c0.y; r[2] = c1.x; r[3] = c1.y;
            r[4] = c2.x; r[5] = c2.y; r[6] = c3.x; r[7] = c3.y;
        }
    }
    __syncthreads();

    int e0 = gbase(scanned, bsum, b * NBLK);
    int e1 = (b == NBUCK - 1) ? E : gbase(scanned, bsum, (b + 1) * NBLK);
    int nE = e1 - e0;
    int j = t & 1;            // half-row (channels 0-7 or 8-15)
    int idx = t >> 1;         // edge slot, strides by 128

    auto edge8 = [&](int p) {
        int s = p & 0x1FFFF, lo = p >> 17;
        int4 w = *(const int4*)(xpre + (size_t)s * 16 + j * 8);
        float2 c0 = __half22float2(*(__half2*)&w.x);
        float2 c1 = __half22float2(*(__half2*)&w.y);
        float2 c2 = __half22float2(*(__half2*)&w.z);
        float2 c3 = __half22float2(*(__half2*)&w.w);
        float* r = acc + lo * 17 + j * 8;
        lds_fadd(r + 0, c0.x); lds_fadd(r + 1, c0.y);
        lds_fadd(r + 2, c1.x); lds_fadd(r + 3, c1.y);
        lds_fadd(r + 4, c2.x); lds_fadd(r + 5, c2.y);
        lds_fadd(r + 6, c3.x); lds_fadd(r + 7, c3.y);
    };

    // 4-deep pipeline
    for (; idx + 384 < nE; idx += 512) {
        int p0 = packed[e0 + idx];
        int p1 = packed[e0 + idx + 128];
        int p2 = packed[e0 + idx + 256];
        int p3 = packed[e0 + idx + 384];
        edge8(p0); edge8(p1); edge8(p2); edge8(p3);
    }
    for (; idx < nE; idx += 128) edge8(packed[e0 + idx]);
    __syncthreads();

    // epilogue: acc1 = dis[d]*rowsum; h = relu(acc1@W1+b1); hpre = dis[d]*(h@W2)
    if (t < ncnt) {
        float d = dis[nbase + t];
        const float* row = acc + t * 17;
        float xi[16];
#pragma unroll
        for (int k = 0; k < 16; ++k) xi[k] = row[k] * d;
        float o0 = 0.f, o1 = 0.f;
#pragma unroll
        for (int c = 0; c < 32; ++c) {
            float h = sb1[c];
#pragma unroll
            for (int k = 0; k < 16; ++k) h = fmaf(xi[k], sW1[k * 32 + c], h);
            h = fmaxf(h, 0.f);
            o0 = fmaf(h, sW2[c * 2 + 0], o0);
            o1 = fmaf(h, sW2[c * 2 + 1], o1);
        }
        hpre[nbase + t] = make_float2(d * o0, d * o1);
    }
}

// ---- phase F: layer-2 aggregation (2 lanes/edge) + bias ---------------------

__global__ void kF_l2(const float* __restrict__ hpre, const float* __restrict__ dis,
                      const int* __restrict__ packed, const int* __restrict__ scanned,
                      const int* __restrict__ bsum, const float* __restrict__ b2,
                      float2* __restrict__ out) {
    __shared__ float a2[64 * 3];
    int t = threadIdx.x, b = blockIdx.x;
    int nbase = b * 64;
    int ncnt = min(64, N - nbase);
    {
        int n = t >> 1, jj = t & 1;
        if (t < 128 && n < ncnt) a2[n * 3 + jj] = hpre[(size_t)(nbase + n) * 2 + jj];
    }
    __syncthreads();
    int e0 = gbase(scanned, bsum, b * NBLK);
    int e1 = (b == NBUCK - 1) ? E : gbase(scanned, bsum, (b + 1) * NBLK);
    int nE = e1 - e0;
    int j = t & 1;
    int idx = t >> 1;
    for (; idx + 384 < nE; idx += 512) {
        int p0 = packed[e0 + idx];
        int p1 = packed[e0 + idx + 128];
        int p2 = packed[e0 + idx + 256];
        int p3 = packed[e0 + idx + 384];
        float v0 = hpre[(size_t)(p0 & 0x1FFFF) * 2 + j];
        float v1 = hpre[(size_t)(p1 & 0x1FFFF) * 2 + j];
        float v2 = hpre[(size_t)(p2 & 0x1FFFF) * 2 + j];
        float v3 = hpre[(size_t)(p3 & 0x1FFFF) * 2 + j];
        lds_fadd(&a2[(p0 >> 17) * 3 + j], v0);
        lds_fadd(&a2[(p1 >> 17) * 3 + j], v1);
        lds_fadd(&a2[(p2 >> 17) * 3 + j], v2);
        lds_fadd(&a2[(p3 >> 17) * 3 + j], v3);
    }
    for (; idx < nE; idx += 128) {
        int p = packed[e0 + idx];
        float vv = hpre[(size_t)(p & 0x1FFFF) * 2 + j];
        lds_fadd(&a2[(p >> 17) * 3 + j], vv);
    }
    __syncthreads();
    if (t < ncnt) {
        float d = dis[nbase + t];
        out[nbase + t] = make_float2(fmaf(d, a2[t * 3 + 0], b2[0]),
                                     fmaf(d, a2[t * 3 + 1], b2[1]));
    }
}

// ---- launcher ---------------------------------------------------------------

extern "C" void kernel_launch(void* const* d_in, const int* in_sizes, int n_in,
                              void* d_out, int out_size, void* d_ws, size_t ws_size,
                              hipStream_t stream) {
    const float* x  = (const float*)d_in[0];
    const int*   ei = (const int*)d_in[1];
    const float* W1 = (const float*)d_in[2];
    const float* b1 = (const float*)d_in[3];
    const float* W2 = (const float*)d_in[4];
    const float* b2 = (const float*)d_in[5];

    const int* src = ei;
    const int* dst = ei + E;

    int*    packed  = (int*)d_ws;                      // E ints
    int*    counts  = packed + E;                      // NSB*B
    int*    scanned = counts + (size_t)NSB * B;        // NSB*B
    int*    bsum    = scanned + (size_t)NSB * B;       // 2048
    float*  dis     = (float*)(bsum + 2048);           // N
    float*  hpre    = dis + N;                         // 2N
    __half* xpre    = (__half*)(hpre + 2 * (size_t)N); // 16N halfs (3.2 MB)

    kA_hist<<<NBLK, B, 0, stream>>>(dst, counts);
    ks1<<<NSB, B, 0, stream>>>(counts, scanned, bsum);
    ks2<<<1, 1024, 0, stream>>>(bsum);
    kC_scatter<<<NBLK, B, 0, stream>>>(src, dst, scanned, bsum, packed);
    kD1_deg<<<NBUCK, B, 0, stream>>>(packed, scanned, bsum, (const float4*)x, dis, xpre);
    kD2_agg<<<NBUCK, B, 0, stream>>>(xpre, dis, packed, scanned, bsum, W1, b1, W2,
                                     (float2*)hpre);
    kF_l2<<<NBUCK, B, 0, stream>>>(hpre, dis, packed, scanned, bsum, b2,
                                   (float2*)d_out);
}

// Round 8
// 153.499 us; speedup vs baseline: 2.0448x; 1.9247x over previous
//
#include <hip/hip_runtime.h>
#include <hip/hip_fp16.h>

static constexpr int N  = 100000;
static constexpr int E  = 1600000;
static constexpr int B  = 256;

static constexpr int NBLK  = 250;                  // partition blocks
static constexpr int CHUNK = E / NBLK;             // 6400 edges per block
static constexpr int PERT  = CHUNK / B;            // 25 edges per thread
static constexpr int NBUCK = (N + 63) / 64;        // 1563 buckets of 64 nodes
static constexpr int NCNT  = NBUCK * NBLK;         // 390750
static constexpr int NSB   = (NCNT + B - 1) / B;   // 1527 scan blocks
static constexpr int CAPD1 = 1536;                 // bucket stage cap (mean 1024, +16 sigma)
static constexpr int CAPD2 = 2560;                 // 2-bucket stage cap (mean 2048)
static constexpr int ROFS_SZ = NBUCK * 64 + 80;    // padded run-offset array

__device__ __forceinline__ int gbase(const int* scanned, const int* bsum, int idx) {
    return scanned[idx] + bsum[idx >> 8];
}

// ---- phase A: per-block bucket histogram ------------------------------------

__global__ void kA_hist(const int* __restrict__ dst, int* __restrict__ counts) {
    __shared__ int hist[NBUCK];
    int t = threadIdx.x, blk = blockIdx.x;
    for (int i = t; i < NBUCK; i += B) hist[i] = 0;
    __syncthreads();
    int eb = blk * CHUNK;
#pragma unroll
    for (int k = 0; k < PERT; ++k) {
        int d = dst[eb + k * B + t];
        atomicAdd(&hist[d >> 6], 1);
    }
    __syncthreads();
    for (int b = t; b < NBUCK; b += B) counts[b * NBLK + blk] = hist[b];
}

// ---- scan -------------------------------------------------------------------

__global__ void ks1(const int* __restrict__ counts, int* __restrict__ scanned,
                    int* __restrict__ bsum) {
    __shared__ int s[B];
    int t = threadIdx.x;
    int g = blockIdx.x * B + t;
    s[t] = (g < NCNT) ? counts[g] : 0;
    __syncthreads();
    for (int off = 1; off < B; off <<= 1) {
        int v = (t >= off) ? s[t - off] : 0;
        __syncthreads();
        s[t] += v;
        __syncthreads();
    }
    if (g < NCNT) scanned[g] = (t == 0) ? 0 : s[t - 1];
    if (t == B - 1) bsum[blockIdx.x] = s[t];
}

__global__ void ks2(int* __restrict__ bsum) {
    __shared__ int s[1024];
    __shared__ int carry_s;
    int t = threadIdx.x;
    if (t == 0) carry_s = 0;
    __syncthreads();
    for (int base = 0; base < NSB; base += 1024) {
        int idx = base + t;
        s[t] = (idx < NSB) ? bsum[idx] : 0;
        __syncthreads();
        for (int off = 1; off < 1024; off <<= 1) {
            int u = (t >= off) ? s[t - off] : 0;
            __syncthreads();
            s[t] += u;
            __syncthreads();
        }
        int carry = carry_s;
        __syncthreads();
        if (idx < NSB) bsum[idx] = carry + ((t == 0) ? 0 : s[t - 1]);
        if (t == 1023) carry_s = carry + s[1023];
        __syncthreads();
    }
}

// ---- phase C: stable partition (bucket-major) with LDS staging --------------

__global__ void kC_scatter(const int* __restrict__ src, const int* __restrict__ dst,
                           const int* __restrict__ scanned, const int* __restrict__ bsum,
                           int* __restrict__ packed) {
    __shared__ int lbase[NBUCK];
    __shared__ int cnt2[NBUCK];
    __shared__ int gb[NBUCK];
    __shared__ int partial[B];
    __shared__ int stage[CHUNK];

    int t = threadIdx.x, blk = blockIdx.x;
    for (int i = t; i < NBUCK; i += B) { lbase[i] = 0; cnt2[i] = 0; }
    __syncthreads();

    int eb = blk * CHUNK;
    int ds[PERT], ss[PERT];
#pragma unroll
    for (int k = 0; k < PERT; ++k) {
        int e = eb + k * B + t;
        ds[k] = dst[e];
        ss[k] = src[e];
        atomicAdd(&lbase[ds[k] >> 6], 1);
    }
    __syncthreads();

    int v[8];
    {
        int i0 = 8 * t, sum = 0;
#pragma unroll
        for (int k = 0; k < 8; ++k) {
            v[k] = (i0 + k < NBUCK) ? lbase[i0 + k] : 0;
            sum += v[k];
        }
        partial[t] = sum;
    }
    __syncthreads();
    for (int off = 1; off < B; off <<= 1) {
        int u = (t >= off) ? partial[t - off] : 0;
        __syncthreads();
        partial[t] += u;
        __syncthreads();
    }
    {
        int run = (t == 0) ? 0 : partial[t - 1];
        int i0 = 8 * t;
#pragma unroll
        for (int k = 0; k < 8; ++k) {
            if (i0 + k < NBUCK) lbase[i0 + k] = run;
            run += v[k];
        }
    }
    for (int b = t; b < NBUCK; b += B)
        gb[b] = gbase(scanned, bsum, b * NBLK + blk);
    __syncthreads();

#pragma unroll
    for (int k = 0; k < PERT; ++k) {
        int d = ds[k], b = d >> 6;
        int r = atomicAdd(&cnt2[b], 1);
        stage[lbase[b] + r] = ss[k] | ((d & 63) << 17);
    }
    __syncthreads();

    for (int slot = t; slot < CHUNK; slot += B) {
        int b = 0;
        for (int step = 1024; step; step >>= 1) {
            int nb = b + step;
            if (nb < NBUCK && lbase[nb] <= slot) b = nb;
        }
        packed[gb[b] + (slot - lbase[b])] = stage[slot];
    }
}

// ---- phase D1: per-bucket node-sort -> sorted runs, rofs, xpre --------------

__global__ void kD1_sort(const int* __restrict__ packed, const int* __restrict__ scanned,
                         const int* __restrict__ bsum, const float4* __restrict__ x4,
                         int* __restrict__ sorted, int* __restrict__ rofs,
                         __half* __restrict__ xpre) {
    __shared__ int c[64], basec[64], cur[64];
    __shared__ int stage2[CAPD1];
    int t = threadIdx.x, b = blockIdx.x;
    if (t < 64) { c[t] = 0; cur[t] = 0; }
    __syncthreads();

    int e0 = gbase(scanned, bsum, b * NBLK);
    int e1 = (b == NBUCK - 1) ? E : gbase(scanned, bsum, (b + 1) * NBLK);
    int ne = e1 - e0;

    // histogram by local node id
    for (int e = e0 + t; e < e1; e += B)
        atomicAdd(&c[packed[e] >> 17], 1);
    __syncthreads();

    // exclusive scan of c -> basec
    if (t < 64) basec[t] = c[t];
    __syncthreads();
    for (int off = 1; off < 64; off <<= 1) {
        int u = (t < 64 && t >= off) ? basec[t - off] : 0;
        __syncthreads();
        if (t < 64) basec[t] += u;
        __syncthreads();
    }
    if (t < 64) basec[t] -= c[t];
    __syncthreads();

    // scatter into node order
    if (ne <= CAPD1) {
        for (int e = e0 + t; e < e1; e += B) {
            int p = packed[e];
            int lo = p >> 17;
            int r = atomicAdd(&cur[lo], 1);
            stage2[basec[lo] + r] = p;
        }
        __syncthreads();
        for (int k = t; k < ne; k += B) sorted[e0 + k] = stage2[k];
    } else {   // overflow fallback (never for this input): direct global scatter
        for (int e = e0 + t; e < e1; e += B) {
            int p = packed[e];
            int lo = p >> 17;
            int r = atomicAdd(&cur[lo], 1);
            sorted[e0 + basec[lo] + r] = p;
        }
    }

    // run offsets (global CSR): rofs[b*64+lo] = e0 + basec[lo]
    if (t < 64) rofs[(size_t)b * 64 + t] = e0 + basec[t];
    if (b == NBUCK - 1 && t < 80) rofs[NBUCK * 64 + t] = E;   // padding

    // xpre = fp16(dis * x) for this bucket's nodes
    int nbase = b * 64;
    {
        int n = t >> 2, j = t & 3;
        int node = nbase + n;
        if (node < N) {
            float d = rsqrtf((float)(c[n] + 1));
            float4 vv = x4[(size_t)node * 4 + j];
            ushort4 pk;
            pk.x = __half_as_ushort(__float2half(vv.x * d));
            pk.y = __half_as_ushort(__float2half(vv.y * d));
            pk.z = __half_as_ushort(__float2half(vv.z * d));
            pk.w = __half_as_ushort(__float2half(vv.w * d));
            *(ushort4*)(xpre + (size_t)node * 16 + j * 4) = pk;
        }
    }
}

// ---- phase D2: layer-1 node-major gather (register acc) + fused dense -------

__global__ void kD2_agg(const __half* __restrict__ xpre, const int* __restrict__ sorted,
                        const int* __restrict__ rofs, const float* __restrict__ W1,
                        const float* __restrict__ b1, const float* __restrict__ W2,
                        float2* __restrict__ hpre) {
    __shared__ float acc[128 * 17];
    __shared__ float sW1[512], sb1[32], sW2[64];
    __shared__ int stageE[CAPD2];
    int t = threadIdx.x;
    int nb0 = blockIdx.x * 128;
    for (int i = t; i < 512; i += B) sW1[i] = W1[i];
    if (t < 32) sb1[t] = b1[t];
    if (t < 64) sW2[t] = W2[t];

    int r0 = rofs[nb0];
    int rend = rofs[nb0 + 128];
    int rlen = rend - r0;
    bool useL = (rlen <= CAPD2);
    if (useL) for (int k = t; k < rlen; k += B) stageE[k] = sorted[r0 + k];
    __syncthreads();

    int nl = t >> 1, h = t & 1;
    int n = nb0 + nl;
    if (n < N) {
        int rs = rofs[n], re = rofs[n + 1];
        float a0, a1, a2, a3, a4, a5, a6, a7;
        {   // self-loop init from fp16 table
            int4 w = *(const int4*)(xpre + (size_t)n * 16 + h * 8);
            float2 q0 = __half22float2(*(__half2*)&w.x);
            float2 q1 = __half22float2(*(__half2*)&w.y);
            float2 q2 = __half22float2(*(__half2*)&w.z);
            float2 q3 = __half22float2(*(__half2*)&w.w);
            a0 = q0.x; a1 = q0.y; a2 = q1.x; a3 = q1.y;
            a4 = q2.x; a5 = q2.y; a6 = q3.x; a7 = q3.y;
        }
        auto add8 = [&](int4 w) {
            float2 q0 = __half22float2(*(__half2*)&w.x);
            float2 q1 = __half22float2(*(__half2*)&w.y);
            float2 q2 = __half22float2(*(__half2*)&w.z);
            float2 q3 = __half22float2(*(__half2*)&w.w);
            a0 += q0.x; a1 += q0.y; a2 += q1.x; a3 += q1.y;
            a4 += q2.x; a5 += q2.y; a6 += q3.x; a7 += q3.y;
        };
        int k = rs;
        for (; k + 4 <= re; k += 4) {
            int w0, w1, w2, w3;
            if (useL) {
                w0 = stageE[k - r0]; w1 = stageE[k + 1 - r0];
                w2 = stageE[k + 2 - r0]; w3 = stageE[k + 3 - r0];
            } else {
                w0 = sorted[k]; w1 = sorted[k + 1];
                w2 = sorted[k + 2]; w3 = sorted[k + 3];
            }
            int4 v0 = *(const int4*)(xpre + (size_t)(w0 & 0x1FFFF) * 16 + h * 8);
            int4 v1 = *(const int4*)(xpre + (size_t)(w1 & 0x1FFFF) * 16 + h * 8);
            int4 v2 = *(const int4*)(xpre + (size_t)(w2 & 0x1FFFF) * 16 + h * 8);
            int4 v3 = *(const int4*)(xpre + (size_t)(w3 & 0x1FFFF) * 16 + h * 8);
            add8(v0); add8(v1); add8(v2); add8(v3);
        }
        for (; k < re; ++k) {
            int w = useL ? stageE[k - r0] : sorted[k];
            add8(*(const int4*)(xpre + (size_t)(w & 0x1FFFF) * 16 + h * 8));
        }
        float* row = acc + nl * 17 + h * 8;
        row[0] = a0; row[1] = a1; row[2] = a2; row[3] = a3;
        row[4] = a4; row[5] = a5; row[6] = a6; row[7] = a7;
    }
    __syncthreads();

    if (t < 128) {
        int n2 = nb0 + t;
        if (n2 < N) {
            int deg = rofs[n2 + 1] - rofs[n2];
            float d = rsqrtf((float)(deg + 1));
            const float* row = acc + t * 17;
            float xi[16];
#pragma unroll
            for (int k = 0; k < 16; ++k) xi[k] = row[k] * d;
            float o0 = 0.f, o1 = 0.f;
#pragma unroll
            for (int c = 0; c < 32; ++c) {
                float hh = sb1[c];
#pragma unroll
                for (int k = 0; k < 16; ++k) hh = fmaf(xi[k], sW1[k * 32 + c], hh);
                hh = fmaxf(hh, 0.f);
                o0 = fmaf(hh, sW2[c * 2 + 0], o0);
                o1 = fmaf(hh, sW2[c * 2 + 1], o1);
            }
            hpre[n2] = make_float2(d * o0, d * o1);
        }
    }
}

// ---- phase F: layer-2 node-major gather (register acc) + bias ---------------

__global__ void kF_l2(const float2* __restrict__ hpre, const int* __restrict__ sorted,
                      const int* __restrict__ rofs, const float* __restrict__ b2,
                      float2* __restrict__ out) {
    int n = blockIdx.x * B + threadIdx.x;
    if (n >= N) return;
    int rs = rofs[n], re = rofs[n + 1];
    float2 self = hpre[n];
    float o0 = self.x, o1 = self.y;
    int k = rs;
    for (; k + 4 <= re; k += 4) {
        int w0 = sorted[k], w1 = sorted[k + 1], w2 = sorted[k + 2], w3 = sorted[k + 3];
        float2 v0 = hpre[w0 & 0x1FFFF];
        float2 v1 = hpre[w1 & 0x1FFFF];
        float2 v2 = hpre[w2 & 0x1FFFF];
        float2 v3 = hpre[w3 & 0x1FFFF];
        o0 += (v0.x + v1.x) + (v2.x + v3.x);
        o1 += (v0.y + v1.y) + (v2.y + v3.y);
    }
    for (; k < re; ++k) {
        float2 v = hpre[sorted[k] & 0x1FFFF];
        o0 += v.x; o1 += v.y;
    }
    float d = rsqrtf((float)(re - rs + 1));
    out[n] = make_float2(fmaf(d, o0, b2[0]), fmaf(d, o1, b2[1]));
}

// ---- launcher ---------------------------------------------------------------

extern "C" void kernel_launch(void* const* d_in, const int* in_sizes, int n_in,
                              void* d_out, int out_size, void* d_ws, size_t ws_size,
                              hipStream_t stream) {
    const float* x  = (const float*)d_in[0];
    const int*   ei = (const int*)d_in[1];
    const float* W1 = (const float*)d_in[2];
    const float* b1 = (const float*)d_in[3];
    const float* W2 = (const float*)d_in[4];
    const float* b2 = (const float*)d_in[5];

    const int* src = ei;
    const int* dst = ei + E;

    // workspace layout (4-byte words; xpre offset is 16 B aligned)
    int*    packed  = (int*)d_ws;                      // E
    int*    sorted  = packed + E;                      // E
    int*    counts  = sorted + E;                      // NSB*B
    int*    scanned = counts + (size_t)NSB * B;        // NSB*B
    int*    bsum    = scanned + (size_t)NSB * B;       // 2048
    int*    rofs    = bsum + 2048;                     // ROFS_SZ (100112)
    float*  hpre    = (float*)(rofs + 100112);         // 2N
    __half* xpre    = (__half*)(hpre + 2 * (size_t)N); // 16N halfs (3.2 MB)

    kA_hist<<<NBLK, B, 0, stream>>>(dst, counts);
    ks1<<<NSB, B, 0, stream>>>(counts, scanned, bsum);
    ks2<<<1, 1024, 0, stream>>>(bsum);
    kC_scatter<<<NBLK, B, 0, stream>>>(src, dst, scanned, bsum, packed);
    kD1_sort<<<NBUCK, B, 0, stream>>>(packed, scanned, bsum, (const float4*)x,
                                      sorted, rofs, xpre);
    kD2_agg<<<(NBUCK + 1) / 2, B, 0, stream>>>(xpre, sorted, rofs, W1, b1, W2,
                                               (float2*)hpre);
    kF_l2<<<(N + B - 1) / B, B, 0, stream>>>((const float2*)hpre, sorted, rofs, b2,
                                             (float2*)d_out);
}

// Round 9
// 131.361 us; speedup vs baseline: 2.3894x; 1.1685x over previous
//
#include <hip/hip_runtime.h>
#include <hip/hip_fp16.h>

static constexpr int N  = 100000;
static constexpr int E  = 1600000;
static constexpr int B  = 256;

static constexpr int NBLK  = 250;                  // kC blocks
static constexpr int CHUNK = E / NBLK;             // 6400 edges per kC block
static constexpr int BC    = 1024;                 // kC block size
static constexpr int NBUCK = (N + 63) / 64;        // 1563 buckets of 64 nodes
static constexpr int SLAB  = 1536;                 // slab capacity per bucket (mean 1024, +16 sigma)

// ---- phase C: hist + slab reservation + stable scatter (one kernel) ---------

__global__ __launch_bounds__(BC, 2) void kC_scatter(
        const int* __restrict__ src, const int* __restrict__ dst,
        int* __restrict__ gcur, int* __restrict__ gslab) {
    __shared__ int lhist[NBUCK];
    __shared__ int lbase[NBUCK];
    __shared__ int gb[NBUCK];
    __shared__ int partial[BC];
    __shared__ int stage[CHUNK];

    int t = threadIdx.x, blk = blockIdx.x;
    for (int i = t; i < NBUCK; i += BC) lhist[i] = 0;
    __syncthreads();

    int eb = blk * CHUNK;
    int ds[7], ss[7];
#pragma unroll
    for (int k = 0; k < 7; ++k) {
        int idx = k * BC + t;
        if (idx < CHUNK) {
            ds[k] = dst[eb + idx];
            ss[k] = src[eb + idx];
            atomicAdd(&lhist[ds[k] >> 6], 1);
        }
    }
    __syncthreads();

    // blocked exclusive scan of lhist -> lbase (2 elems/thread)
    int i0 = 2 * t;
    int v0 = (i0 < NBUCK) ? lhist[i0] : 0;
    int v1 = (i0 + 1 < NBUCK) ? lhist[i0 + 1] : 0;
    partial[t] = v0 + v1;
    __syncthreads();
    for (int off = 1; off < BC; off <<= 1) {
        int u = (t >= off) ? partial[t - off] : 0;
        __syncthreads();
        partial[t] += u;
        __syncthreads();
    }
    {
        int run = (t == 0) ? 0 : partial[t - 1];
        if (i0 < NBUCK) lbase[i0] = run;
        if (i0 + 1 < NBUCK) lbase[i0 + 1] = run + v0;
    }
    // reserve slab space per nonempty bucket; reuse lhist as scatter cursor
    for (int bb = t; bb < NBUCK; bb += BC) {
        int h = lhist[bb];
        if (h > 0) gb[bb] = bb * SLAB + atomicAdd(&gcur[bb], h);
        lhist[bb] = 0;
    }
    __syncthreads();

    // scatter into LDS stage, bucket-major; packed = (dst&63)<<17 | src
#pragma unroll
    for (int k = 0; k < 7; ++k) {
        int idx = k * BC + t;
        if (idx < CHUNK) {
            int d = ds[k], b = d >> 6;
            int r = atomicAdd(&lhist[b], 1);
            stage[lbase[b] + r] = ss[k] | ((d & 63) << 17);
        }
    }
    __syncthreads();

    // write runs to global slabs (coalesced within runs)
    for (int slot = t; slot < CHUNK; slot += BC) {
        int b = 0;
        for (int step = 1024; step; step >>= 1) {
            int nb = b + step;
            if (nb < NBUCK && lbase[nb] <= slot) b = nb;
        }
        gslab[gb[b] + (slot - lbase[b])] = stage[slot];
    }
}

// ---- phase D1: per-bucket in-place node sort -> rofs (65-stride CSR), xpre --

__global__ void kD1_sort(const int* __restrict__ gcur, int* __restrict__ gslab,
                         int* __restrict__ rofs, const float4* __restrict__ x4,
                         __half* __restrict__ xpre) {
    __shared__ int st0[SLAB], st1[SLAB];
    __shared__ int c[64], basec[64], cur[64];
    int t = threadIdx.x, b = blockIdx.x;
    if (t < 64) { c[t] = 0; cur[t] = 0; }
    __syncthreads();

    int ne = gcur[b]; if (ne > SLAB) ne = SLAB;
    int base = b * SLAB;
    for (int k = t; k < ne; k += B) {
        int p = gslab[base + k];
        st0[k] = p;
        atomicAdd(&c[p >> 17], 1);
    }
    __syncthreads();

    if (t < 64) basec[t] = c[t];
    __syncthreads();
    for (int off = 1; off < 64; off <<= 1) {
        int u = (t < 64 && t >= off) ? basec[t - off] : 0;
        __syncthreads();
        if (t < 64) basec[t] += u;
        __syncthreads();
    }
    if (t < 64) basec[t] -= c[t];
    __syncthreads();

    for (int k = t; k < ne; k += B) {
        int p = st0[k];
        int lo = p >> 17;
        int r = atomicAdd(&cur[lo], 1);
        st1[basec[lo] + r] = p;
    }
    __syncthreads();
    for (int k = t; k < ne; k += B) gslab[base + k] = st1[k];

    if (t < 64) rofs[b * 65 + t] = base + basec[t];
    if (t == 64) rofs[b * 65 + 64] = base + ne;

    // xpre = fp16(dis * x) for this bucket's 64 nodes (4 lanes/node)
    int n = t >> 2, j = t & 3;
    int node = b * 64 + n;
    if (node < N) {
        float d = rsqrtf((float)(c[n] + 1));
        float4 vv = x4[(size_t)node * 4 + j];
        ushort4 pk;
        pk.x = __half_as_ushort(__float2half(vv.x * d));
        pk.y = __half_as_ushort(__float2half(vv.y * d));
        pk.z = __half_as_ushort(__float2half(vv.z * d));
        pk.w = __half_as_ushort(__float2half(vv.w * d));
        *(ushort4*)(xpre + (size_t)node * 16 + j * 4) = pk;
    }
}

// ---- phase D2: layer-1 node-major gather (register acc) + fused dense -------

__global__ void kD2_agg(const __half* __restrict__ xpre, const int* __restrict__ gslab,
                        const int* __restrict__ rofs, const float* __restrict__ W1,
                        const float* __restrict__ b1, const float* __restrict__ W2,
                        float2* __restrict__ hpre) {
    __shared__ float acc[128 * 17];
    __shared__ float sW1[512], sb1[32], sW2[64];
    int t = threadIdx.x;
    int nb0 = blockIdx.x * 128;
    for (int i = t; i < 512; i += B) sW1[i] = W1[i];
    if (t < 32) sb1[t] = b1[t];
    if (t < 64) sW2[t] = W2[t];

    int nl = t >> 1, h = t & 1;
    int n = nb0 + nl;
    if (n < N) {
        int bb = n >> 6, lo = n & 63;
        int rs = rofs[bb * 65 + lo], re = rofs[bb * 65 + lo + 1];
        float a0, a1, a2, a3, a4, a5, a6, a7;
        {   // self-loop init from fp16 table
            int4 w = *(const int4*)(xpre + (size_t)n * 16 + h * 8);
            float2 q0 = __half22float2(*(__half2*)&w.x);
            float2 q1 = __half22float2(*(__half2*)&w.y);
            float2 q2 = __half22float2(*(__half2*)&w.z);
            float2 q3 = __half22float2(*(__half2*)&w.w);
            a0 = q0.x; a1 = q0.y; a2 = q1.x; a3 = q1.y;
            a4 = q2.x; a5 = q2.y; a6 = q3.x; a7 = q3.y;
        }
        auto add8 = [&](int4 w) {
            float2 q0 = __half22float2(*(__half2*)&w.x);
            float2 q1 = __half22float2(*(__half2*)&w.y);
            float2 q2 = __half22float2(*(__half2*)&w.z);
            float2 q3 = __half22float2(*(__half2*)&w.w);
            a0 += q0.x; a1 += q0.y; a2 += q1.x; a3 += q1.y;
            a4 += q2.x; a5 += q2.y; a6 += q3.x; a7 += q3.y;
        };
        int k = rs;
        for (; k + 4 <= re; k += 4) {
            int w0 = gslab[k], w1 = gslab[k + 1], w2 = gslab[k + 2], w3 = gslab[k + 3];
            int4 v0 = *(const int4*)(xpre + (size_t)(w0 & 0x1FFFF) * 16 + h * 8);
            int4 v1 = *(const int4*)(xpre + (size_t)(w1 & 0x1FFFF) * 16 + h * 8);
            int4 v2 = *(const int4*)(xpre + (size_t)(w2 & 0x1FFFF) * 16 + h * 8);
            int4 v3 = *(const int4*)(xpre + (size_t)(w3 & 0x1FFFF) * 16 + h * 8);
            add8(v0); add8(v1); add8(v2); add8(v3);
        }
        for (; k < re; ++k)
            add8(*(const int4*)(xpre + (size_t)(gslab[k] & 0x1FFFF) * 16 + h * 8));
        float* row = acc + nl * 17 + h * 8;
        row[0] = a0; row[1] = a1; row[2] = a2; row[3] = a3;
        row[4] = a4; row[5] = a5; row[6] = a6; row[7] = a7;
    }
    __syncthreads();

    if (t < 128) {
        int n2 = nb0 + t;
        if (n2 < N) {
            int bb = n2 >> 6, lo = n2 & 63;
            int deg = rofs[bb * 65 + lo + 1] - rofs[bb * 65 + lo];
            float d = rsqrtf((float)(deg + 1));
            const float* row = acc + t * 17;
            float xi[16];
#pragma unroll
            for (int k = 0; k < 16; ++k) xi[k] = row[k] * d;
            float o0 = 0.f, o1 = 0.f;
#pragma unroll
            for (int c = 0; c < 32; ++c) {
                float hh = sb1[c];
#pragma unroll
                for (int k = 0; k < 16; ++k) hh = fmaf(xi[k], sW1[k * 32 + c], hh);
                hh = fmaxf(hh, 0.f);
                o0 = fmaf(hh, sW2[c * 2 + 0], o0);
                o1 = fmaf(hh, sW2[c * 2 + 1], o1);
            }
            hpre[n2] = make_float2(d * o0, d * o1);
        }
    }
}

// ---- phase F: layer-2 node-major gather + bias ------------------------------

__global__ void kF_l2(const float2* __restrict__ hpre, const int* __restrict__ gslab,
                      const int* __restrict__ rofs, const float* __restrict__ b2,
                      float2* __restrict__ out) {
    int n = blockIdx.x * B + threadIdx.x;
    if (n >= N) return;
    int bb = n >> 6, lo = n & 63;
    int rs = rofs[bb * 65 + lo], re = rofs[bb * 65 + lo + 1];
    float2 self = hpre[n];
    float o0 = self.x, o1 = self.y;
    int k = rs;
    for (; k + 4 <= re; k += 4) {
        int w0 = gslab[k], w1 = gslab[k + 1], w2 = gslab[k + 2], w3 = gslab[k + 3];
        float2 v0 = hpre[w0 & 0x1FFFF];
        float2 v1 = hpre[w1 & 0x1FFFF];
        float2 v2 = hpre[w2 & 0x1FFFF];
        float2 v3 = hpre[w3 & 0x1FFFF];
        o0 += (v0.x + v1.x) + (v2.x + v3.x);
        o1 += (v0.y + v1.y) + (v2.y + v3.y);
    }
    for (; k < re; ++k) {
        float2 v = hpre[gslab[k] & 0x1FFFF];
        o0 += v.x; o1 += v.y;
    }
    float d = rsqrtf((float)(re - rs + 1));
    out[n] = make_float2(fmaf(d, o0, b2[0]), fmaf(d, o1, b2[1]));
}

// ---- launcher ---------------------------------------------------------------

extern "C" void kernel_launch(void* const* d_in, const int* in_sizes, int n_in,
                              void* d_out, int out_size, void* d_ws, size_t ws_size,
                              hipStream_t stream) {
    const float* x  = (const float*)d_in[0];
    const int*   ei = (const int*)d_in[1];
    const float* W1 = (const float*)d_in[2];
    const float* b1 = (const float*)d_in[3];
    const float* W2 = (const float*)d_in[4];
    const float* b2 = (const float*)d_in[5];

    const int* src = ei;
    const int* dst = ei + E;

    // workspace layout (4-byte words; paddings keep xpre 16 B aligned)
    int*    gslab = (int*)d_ws;                        // NBUCK*SLAB = 2,400,768
    int*    rofs  = gslab + (size_t)NBUCK * SLAB;      // NBUCK*65+1 -> pad 101,600
    int*    gcur  = rofs + 101600;                     // NBUCK -> pad 1,600
    float*  hpre  = (float*)(gcur + 1600);             // 2N
    __half* xpre  = (__half*)(hpre + 2 * (size_t)N);   // 16N halfs (3.2 MB)

    hipMemsetAsync(gcur, 0, NBUCK * sizeof(int), stream);
    kC_scatter<<<NBLK, BC, 0, stream>>>(src, dst, gcur, gslab);
    kD1_sort<<<NBUCK, B, 0, stream>>>(gcur, gslab, rofs, (const float4*)x, xpre);
    kD2_agg<<<(N + 127) / 128, B, 0, stream>>>(xpre, gslab, rofs, W1, b1, W2,
                                               (float2*)hpre);
    kF_l2<<<(N + B - 1) / B, B, 0, stream>>>((const float2*)hpre, gslab, rofs, b2,
                                             (float2*)d_out);
}